// Round 11
// baseline (186.580 us; speedup 1.0000x reference)
//
#include <hip/hip_runtime.h>
#include <hip/hip_bf16.h>

#define N_NODES 200000
#define E1 1600000
#define N1P 100000
#define E2P 100000
#define N2P 50000
#define BGR 1000
#define C1 32
#define C2 64
#define HIDN 25
#define NCLS 10

typedef short short8 __attribute__((ext_vector_type(8)));
typedef int int4v __attribute__((ext_vector_type(4)));
typedef float f32x4 __attribute__((ext_vector_type(4)));
typedef float f32x2 __attribute__((ext_vector_type(2)));

union FragU { int4v i; short8 s; };

__device__ __forceinline__ float elu1(float v) {
    return v > 0.f ? v : expm1f(v);
}
__device__ __forceinline__ float bf2f(unsigned short u) {
    return __uint_as_float(((unsigned int)u) << 16);
}
__device__ __forceinline__ unsigned int pk_bf16(float a, float b) {
    unsigned int r;
    asm("v_cvt_pk_bf16_f32 %0, %1, %2" : "=v"(r) : "v"(a), "v"(b));
    return r;
}
__device__ __forceinline__ void atomic_pk_bf16(unsigned short* p, unsigned int pk) {
    asm volatile("global_atomic_pk_add_bf16 %0, %1, off" :: "v"(p), "v"(pk) : "memory");
}

// ---------------- fused fragment builders
// blk 0-1:  conv1 B [32][32] (rows 0-24 w2, 25 b2, 26-31 zero), even/odd col perm:
//           MFMA m, col c -> channel 2c+m.  W2f[(m*64+lane)*4+slot]
// blk 2+:   conv2 B [832][64], col perm: MFMA nb, col c -> ch (nb>>1)*32 + 2c + (nb&1)
__global__ __launch_bounds__(256) void bgbuild_kernel(
    const float* __restrict__ w2a, const float* __restrict__ b2a,
    const float* __restrict__ w2b, const float* __restrict__ b2b,
    unsigned int* __restrict__ W2f, unsigned int* __restrict__ Bg)
{
    int blk = blockIdx.x, t = threadIdx.x;
    if (blk < 2) {
        int q = blk * 256 + t;                  // 512 u32 total
        int jj = q & 3, l = (q >> 2) & 63, m = q >> 8;
        int k0 = (l >> 4) * 8 + 2 * jj;
        int o = 2 * (l & 15) + m;
        float v0 = (k0 < 25) ? w2a[k0 * 32 + o] : (k0 == 25 ? b2a[o] : 0.f);
        int k1 = k0 + 1;
        float v1 = (k1 < 25) ? w2a[k1 * 32 + o] : (k1 == 25 ? b2a[o] : 0.f);
        W2f[q] = pk_bf16(v0, v1);
    } else {
        int idx = (blk - 2) * 256 + t;          // 26624 pairs
        if (idx >= 26 * 4 * 64 * 4) return;
        int g0 = idx * 2;
        int j = g0 & 7;
        int l = (g0 >> 3) & 63;
        int nb = (g0 >> 9) & 3;
        int kt = g0 >> 11;
        int k = kt * 32 + (l >> 4) * 8 + j;
        int o = (nb >> 1) * 32 + 2 * (l & 15) + (nb & 1);
        float v0, v1;
        if (k < 800) { v0 = w2b[k * 64 + o]; v1 = w2b[(k + 1) * 64 + o]; }
        else         { v0 = b2b[(k - 800) * 64 + o]; v1 = b2b[(k - 799) * 64 + o]; }
        Bg[idx] = pk_bf16(v0, v1);
    }
}

// ---------------- conv1 via MFMA; epilogue = packed bf16 atomics, full 64B row/instr
__global__ __launch_bounds__(256) void conv1_kernel(
    const float* __restrict__ x, const float* __restrict__ ea,
    const int* __restrict__ ei,
    const float* __restrict__ w1, const float* __restrict__ b1,
    const unsigned int* __restrict__ W2f,
    unsigned short* __restrict__ agg1b)
{
    __shared__ unsigned int afrag[16][4][64];   // 16 KB
    __shared__ int dst_lds[256];

    int t = threadIdx.x;
    int e = blockIdx.x * 256 + t;               // E1 % 256 == 0
    f32x2 a = ((const f32x2*)ea)[e];
    int s = ei[e], d = ei[E1 + e];
    float xv = x[s];
    dst_lds[t] = d;

    float v[26];
#pragma unroll
    for (int h = 0; h < HIDN; ++h) {
        float u = fmaf(a.x, w1[h], fmaf(a.y, w1[HIDN + h], b1[h]));
        v[h] = fmaxf(u, 0.f) * xv;
    }
    v[25] = xv;

    int tile = t >> 4, r16 = t & 15;
#pragma unroll
    for (int p = 0; p < 13; ++p) {              // pair p covers k = 2p, 2p+1
        int g = p >> 2, j = p & 3;
        afrag[tile][j][g * 16 + r16] = pk_bf16(v[2 * p], v[2 * p + 1]);
    }
    afrag[tile][1][48 + r16] = 0;               // k = 26..31 zero
    afrag[tile][2][48 + r16] = 0;
    afrag[tile][3][48 + r16] = 0;
    __syncthreads();

    int lane = t & 63, wave = t >> 6;
    FragU bf0, bf1;
    bf0.i = *(const int4v*)(W2f + lane * 4);
    bf1.i = *(const int4v*)(W2f + (64 + lane) * 4);
    int c = lane & 15, rg = lane >> 4;

#pragma unroll
    for (int ti = 0; ti < 4; ++ti) {
        int tl = wave * 4 + ti;
        FragU af;
        af.i.x = afrag[tl][0][lane];
        af.i.y = afrag[tl][1][lane];
        af.i.z = afrag[tl][2][lane];
        af.i.w = afrag[tl][3][lane];
        f32x4 a0 = (f32x4){0.f, 0.f, 0.f, 0.f};
        f32x4 a1 = (f32x4){0.f, 0.f, 0.f, 0.f};
        a0 = __builtin_amdgcn_mfma_f32_16x16x32_bf16(af.s, bf0.s, a0, 0, 0, 0);
        a1 = __builtin_amdgcn_mfma_f32_16x16x32_bf16(af.s, bf1.s, a1, 0, 0, 0);
#pragma unroll
        for (int jj = 0; jj < 4; ++jj) {
            int le = tl * 16 + rg * 4 + jj;
            // lane c holds channels (2c, 2c+1) -> one pk atomic, rows fully covered
            atomic_pk_bf16(agg1b + (size_t)dst_lds[le] * C1 + 2 * c,
                           pk_bf16(a0[jj], a1[jj]));
        }
    }
}

// ---------------- finish conv1 (root+bias+elu) and pool1 (pairwise max) + pos mean
__global__ __launch_bounds__(256) void pool1_kernel(
    const unsigned short* __restrict__ agg1b, const float* __restrict__ x,
    const float* __restrict__ root1, const float* __restrict__ bias1,
    const float* __restrict__ pos, unsigned short* __restrict__ x1b,
    float* __restrict__ pos1)
{
    int t = blockIdx.x * blockDim.x + threadIdx.x;
    if (t >= N1P * C1) return;
    int j = t >> 5, o = t & 31;
    int na = 2 * j, nb = 2 * j + 1;
    float r = root1[o], bo = bias1[o];
    float ha = elu1(bf2f(agg1b[(size_t)na * C1 + o]) + x[na] * r + bo);
    float hb = elu1(bf2f(agg1b[(size_t)nb * C1 + o]) + x[nb] * r + bo);
    float mx = fmaxf(ha, hb);
    x1b[t] = (unsigned short)(pk_bf16(mx, mx) & 0xffffu);
    if (o < 2) pos1[j * 2 + o] = 0.5f * (pos[na * 2 + o] + pos[nb * 2 + o]);
}

// ---------------- global max|cart| over pooled edges
__global__ __launch_bounds__(256) void maxabs_kernel(
    const int* __restrict__ ei2, const float* __restrict__ pos1,
    unsigned int* __restrict__ maxbits)
{
    int e = blockIdx.x * blockDim.x + threadIdx.x;
    float m = 0.f;
    if (e < E2P) {
        int s = ei2[e], d = ei2[E2P + e];
        float c0 = pos1[2 * s] - pos1[2 * d];
        float c1 = pos1[2 * s + 1] - pos1[2 * d + 1];
        m = fmaxf(fabsf(c0), fabsf(c1));
    }
#pragma unroll
    for (int off = 32; off; off >>= 1)
        m = fmaxf(m, __shfl_down(m, off));
    if ((threadIdx.x & 63) == 0)
        atomicMax(maxbits, __float_as_uint(m));
}

// ---------------- conv2 via MFMA: 128 edges/block (782 blocks), bf16 hid in LDS,
// software-prefetched B fragments, pk-bf16 atomic epilogue  [round-7 exact, known good]
__global__ __launch_bounds__(256) void conv2_kernel(
    const int* __restrict__ ei2, const float* __restrict__ pos1,
    const unsigned short* __restrict__ x1b,
    const float* __restrict__ w1, const float* __restrict__ b1,
    const unsigned int* __restrict__ maxbits,
    const unsigned int* __restrict__ Bg,
    unsigned short* __restrict__ agg2b)
{
    __shared__ __align__(16) unsigned short xs_lds[128][40];  // 10.2 KB
    __shared__ unsigned int hidb[128][14];                     // 7.2 KB (13 pairs+pad)
    __shared__ int dst_lds[128];

    int t = threadIdx.x;
    int base = blockIdx.x * 128;

    if (t < 128) {   // stage one edge per thread
        int ge = base + t;
        bool ok = ge < E2P;
        float inv = 0.5f / __uint_as_float(maxbits[0]);
        int s = 0, d = 0;
        if (ok) { s = ei2[ge]; d = ei2[E2P + ge]; }
        dst_lds[t] = d;
        float a0 = (pos1[2 * s] - pos1[2 * d]) * inv + 0.5f;
        float a1 = (pos1[2 * s + 1] - pos1[2 * d + 1]) * inv + 0.5f;
        float hv[26];
#pragma unroll
        for (int h = 0; h < HIDN; ++h) {
            float u = fmaf(a0, w1[h], fmaf(a1, w1[HIDN + h], b1[h]));
            hv[h] = ok ? fmaxf(u, 0.f) : 0.f;
        }
        hv[25] = 0.f;
#pragma unroll
        for (int p = 0; p < 13; ++p)
            hidb[t][p] = pk_bf16(hv[2 * p], hv[2 * p + 1]);
        const int4v* xp = (const int4v*)(x1b + (size_t)s * C1);
#pragma unroll
        for (int q = 0; q < 4; ++q) {
            int4v z4 = (int4v){0, 0, 0, 0};
            *(int4v*)&xs_lds[t][q * 8] = ok ? xp[q] : z4;
        }
    }
    __syncthreads();

    int lane = t & 63, wave = t >> 6;
    int c = lane & 15, rg = lane >> 4;

    FragU xv2[2];
    float xfl[2][8];
#pragma unroll
    for (int ti = 0; ti < 2; ++ti) {
        int row = (wave * 2 + ti) * 16 + c;
        xv2[ti].i = *(const int4v*)&xs_lds[row][rg * 8];
#pragma unroll
        for (int g2 = 0; g2 < 4; ++g2) {
            unsigned int u = (unsigned int)xv2[ti].i[g2];
            xfl[ti][2 * g2]     = __uint_as_float(u << 16);
            xfl[ti][2 * g2 + 1] = __uint_as_float(u & 0xffff0000u);
        }
    }

    f32x4 acc[2][4];
#pragma unroll
    for (int ti = 0; ti < 2; ++ti)
#pragma unroll
        for (int nb = 0; nb < 4; ++nb)
            acc[ti][nb] = (f32x4){0.f, 0.f, 0.f, 0.f};

    const int4v* Bg4 = (const int4v*)Bg;
    FragU bf[4];
#pragma unroll
    for (int nb = 0; nb < 4; ++nb)
        bf[nb].i = Bg4[nb * 64 + lane];          // kt = 0

#pragma unroll
    for (int kt = 0; kt < 25; ++kt) {
        FragU bn[4];                             // prefetch kt+1 (kt=24 -> b2 frags)
#pragma unroll
        for (int nb = 0; nb < 4; ++nb)
            bn[nb].i = Bg4[((kt + 1) * 4 + nb) * 64 + lane];
#pragma unroll
        for (int ti = 0; ti < 2; ++ti) {
            unsigned int hu = hidb[(wave * 2 + ti) * 16 + c][kt >> 1];
            float hvv = bf2f((unsigned short)((kt & 1) ? (hu >> 16) : (hu & 0xffffu)));
            FragU af;
            af.i.x = pk_bf16(hvv * xfl[ti][0], hvv * xfl[ti][1]);
            af.i.y = pk_bf16(hvv * xfl[ti][2], hvv * xfl[ti][3]);
            af.i.z = pk_bf16(hvv * xfl[ti][4], hvv * xfl[ti][5]);
            af.i.w = pk_bf16(hvv * xfl[ti][6], hvv * xfl[ti][7]);
#pragma unroll
            for (int nb = 0; nb < 4; ++nb)
                acc[ti][nb] = __builtin_amdgcn_mfma_f32_16x16x32_bf16(af.s, bf[nb].s, acc[ti][nb], 0, 0, 0);
        }
#pragma unroll
        for (int nb = 0; nb < 4; ++nb) bf[nb] = bn[nb];
    }
    // kt = 25: b2 term, A = xs directly
#pragma unroll
    for (int ti = 0; ti < 2; ++ti)
#pragma unroll
        for (int nb = 0; nb < 4; ++nb)
            acc[ti][nb] = __builtin_amdgcn_mfma_f32_16x16x32_bf16(xv2[ti].s, bf[nb].s, acc[ti][nb], 0, 0, 0);

    // epilogue: lane c holds channels (2c,2c+1) [nb 0,1] and (32+2c,32+2c+1) [nb 2,3]
#pragma unroll
    for (int ti = 0; ti < 2; ++ti) {
        int tl = wave * 2 + ti;
#pragma unroll
        for (int jj = 0; jj < 4; ++jj) {
            int le = tl * 16 + rg * 4 + jj;
            if (base + le < E2P) {
                unsigned short* dp = agg2b + (size_t)dst_lds[le] * C2;
                atomic_pk_bf16(dp + 2 * c,      pk_bf16(acc[ti][0][jj], acc[ti][1][jj]));
                atomic_pk_bf16(dp + 32 + 2 * c, pk_bf16(acc[ti][2][jj], acc[ti][3][jj]));
            }
        }
    }
}

// ---------------- fused: finish conv2 (root2+bias2+elu), pool2 (pairwise max),
// per-graph mean, then FC head + log_softmax
// [NEW this round: r2[32] register hoist + vectorized x1b loads]
__global__ __launch_bounds__(256) void pool2_head_kernel(
    const unsigned short* __restrict__ agg2b, const unsigned short* __restrict__ x1b,
    const float* __restrict__ root2, const float* __restrict__ bias2,
    const float* __restrict__ fc1w, const float* __restrict__ fc1b,
    const float* __restrict__ fc2w, const float* __restrict__ fc2b,
    float* __restrict__ out)
{
    int b = blockIdx.x;
    int t = threadIdx.x;
    int w = t >> 6, o = t & 63;
    __shared__ float part[4][C2];
    __shared__ float gs[C2];
    __shared__ float zs[128];
    __shared__ float ls[NCLS];

    // hoist root2 column o (reused for all 26 node evaluations per thread)
    float r2[C1];
#pragma unroll
    for (int i = 0; i < C1; ++i) r2[i] = root2[i * C2 + o];
    float bo = bias2[o];

    float sum = 0.f;
    for (int jj = w; jj < 50; jj += 4) {
        int j = b * 50 + jj;
        float hv[2];
#pragma unroll
        for (int tt = 0; tt < 2; ++tt) {
            int n = 2 * j + tt;
            float a = bf2f(agg2b[(size_t)n * C2 + o]) + bo;
            const int4v* xp = (const int4v*)(x1b + (size_t)n * C1);
#pragma unroll
            for (int q = 0; q < 4; ++q) {
                int4v v4 = xp[q];
#pragma unroll
                for (int g2 = 0; g2 < 4; ++g2) {
                    unsigned int u = (unsigned int)v4[g2];
                    a = fmaf(__uint_as_float(u << 16),         r2[q * 8 + 2 * g2],     a);
                    a = fmaf(__uint_as_float(u & 0xffff0000u), r2[q * 8 + 2 * g2 + 1], a);
                }
            }
            hv[tt] = elu1(a);
        }
        sum += fmaxf(hv[0], hv[1]);
    }
    part[w][o] = sum;
    __syncthreads();
    if (w == 0)
        gs[o] = (part[0][o] + part[1][o] + part[2][o] + part[3][o]) * (1.f / 50.f);
    __syncthreads();
    if (t < 128) {
        float z = fc1b[t];
#pragma unroll
        for (int i = 0; i < C2; ++i) z = fmaf(gs[i], fc1w[i * 128 + t], z);
        zs[t] = elu1(z);
    }
    __syncthreads();
    if (t < NCLS) {
        float l = fc2b[t];
#pragma unroll
        for (int k = 0; k < 128; ++k) l = fmaf(zs[k], fc2w[k * NCLS + t], l);
        ls[t] = l;
    }
    __syncthreads();
    if (t < NCLS) {
        float mx = ls[0];
#pragma unroll
        for (int cc = 1; cc < NCLS; ++cc) mx = fmaxf(mx, ls[cc]);
        float se = 0.f;
#pragma unroll
        for (int cc = 0; cc < NCLS; ++cc) se += expf(ls[cc] - mx);
        out[b * NCLS + t] = ls[t] - mx - logf(se);
    }
}

extern "C" void kernel_launch(void* const* d_in, const int* in_sizes, int n_in,
                              void* d_out, int out_size, void* d_ws, size_t ws_size,
                              hipStream_t stream)
{
    const float* x    = (const float*)d_in[0];
    const float* pos  = (const float*)d_in[1];
    const int*   ei   = (const int*)d_in[2];
    const float* ea   = (const float*)d_in[3];
    const int*   ei2  = (const int*)d_in[6];
    const float* n1w1 = (const float*)d_in[8];
    const float* n1b1 = (const float*)d_in[9];
    const float* n1w2 = (const float*)d_in[10];
    const float* n1b2 = (const float*)d_in[11];
    const float* root1= (const float*)d_in[12];
    const float* bias1= (const float*)d_in[13];
    const float* n2w1 = (const float*)d_in[14];
    const float* n2b1 = (const float*)d_in[15];
    const float* n2w2 = (const float*)d_in[16];
    const float* n2b2 = (const float*)d_in[17];
    const float* root2= (const float*)d_in[18];
    const float* bias2= (const float*)d_in[19];
    const float* fc1w = (const float*)d_in[20];
    const float* fc1b = (const float*)d_in[21];
    const float* fc2w = (const float*)d_in[22];
    const float* fc2b = (const float*)d_in[23];
    float* out = (float*)d_out;

    char* w = (char*)d_ws;
    unsigned short* agg1b = (unsigned short*)w;  w += (size_t)N_NODES * C1 * 2;   // 12.8 MB
    unsigned short* x1b   = (unsigned short*)w;  w += (size_t)N1P * C1 * 2;       // 6.4 MB
    float* pos1 = (float*)w;                     w += (size_t)N1P * 2 * 4;        // 0.8 MB
    unsigned int* maxbits = (unsigned int*)w;    w += 256;
    unsigned short* agg2b = (unsigned short*)w;  w += (size_t)N1P * C2 * 2;       // 12.8 MB
    unsigned int* Bg = (unsigned int*)w;         w += 26624 * 4;
    unsigned int* W2f = (unsigned int*)w;        w += 512 * 4;

    hipMemsetAsync(agg1b, 0, (size_t)N_NODES * C1 * 2, stream);
    hipMemsetAsync(agg2b, 0, (size_t)N1P * C2 * 2, stream);
    hipMemsetAsync(maxbits, 0, 256, stream);

    bgbuild_kernel<<<106, 256, 0, stream>>>(n1w2, n1b2, n2w2, n2b2, W2f, Bg);
    conv1_kernel<<<E1 / 256, 256, 0, stream>>>(x, ea, ei, n1w1, n1b1, W2f, agg1b);
    pool1_kernel<<<(N1P * C1 + 255) / 256, 256, 0, stream>>>(agg1b, x, root1, bias1, pos, x1b, pos1);
    maxabs_kernel<<<(E2P + 255) / 256, 256, 0, stream>>>(ei2, pos1, maxbits);
    conv2_kernel<<<(E2P + 127) / 128, 256, 0, stream>>>(ei2, pos1, x1b, n2w1, n2b1, maxbits, Bg, agg2b);
    pool2_head_kernel<<<BGR, 256, 0, stream>>>(agg2b, x1b, root2, bias2,
                                               fc1w, fc1b, fc2w, fc2b, out);
}

// Round 12
// 165.341 us; speedup vs baseline: 1.1285x; 1.1285x over previous
//
#include <hip/hip_runtime.h>
#include <hip/hip_bf16.h>

#define N_NODES 200000
#define E1 1600000
#define N1P 100000
#define E2P 100000
#define N2P 50000
#define BGR 1000
#define C1 32
#define C2 64
#define HIDN 25
#define NCLS 10

typedef short short8 __attribute__((ext_vector_type(8)));
typedef int int4v __attribute__((ext_vector_type(4)));
typedef float f32x4 __attribute__((ext_vector_type(4)));
typedef float f32x2 __attribute__((ext_vector_type(2)));

union FragU { int4v i; short8 s; };

__device__ __forceinline__ float elu1(float v) {
    return v > 0.f ? v : expm1f(v);
}
__device__ __forceinline__ float bf2f(unsigned short u) {
    return __uint_as_float(((unsigned int)u) << 16);
}
__device__ __forceinline__ unsigned int pk_bf16(float a, float b) {
    unsigned int r;
    asm("v_cvt_pk_bf16_f32 %0, %1, %2" : "=v"(r) : "v"(a), "v"(b));
    return r;
}
__device__ __forceinline__ void atomic_pk_bf16(unsigned short* p, unsigned int pk) {
    asm volatile("global_atomic_pk_add_bf16 %0, %1, off" :: "v"(p), "v"(pk) : "memory");
}

// ---------------- fused: fragment builders + global max|cart| (from pos directly)
// blk 0-1:  conv1 B [32][32], even/odd col perm -> W2f
// blk 2+:   conv2 B [832][64], col perm -> Bg
// all blks: grid-stride maxabs over pooled edges
__global__ __launch_bounds__(256) void bgbuild_kernel(
    const float* __restrict__ w2a, const float* __restrict__ b2a,
    const float* __restrict__ w2b, const float* __restrict__ b2b,
    const float* __restrict__ pos, const int* __restrict__ ei2,
    unsigned int* __restrict__ W2f, unsigned int* __restrict__ Bg,
    unsigned int* __restrict__ maxbits)
{
    int blk = blockIdx.x, t = threadIdx.x;
    if (blk < 2) {
        int q = blk * 256 + t;                  // 512 u32 total
        int jj = q & 3, l = (q >> 2) & 63, m = q >> 8;
        int k0 = (l >> 4) * 8 + 2 * jj;
        int o = 2 * (l & 15) + m;
        float v0 = (k0 < 25) ? w2a[k0 * 32 + o] : (k0 == 25 ? b2a[o] : 0.f);
        int k1 = k0 + 1;
        float v1 = (k1 < 25) ? w2a[k1 * 32 + o] : (k1 == 25 ? b2a[o] : 0.f);
        W2f[q] = pk_bf16(v0, v1);
    } else {
        int idx = (blk - 2) * 256 + t;          // 26624 pairs exactly
        if (idx < 26 * 4 * 64 * 4) {
            int g0 = idx * 2;
            int j = g0 & 7;
            int l = (g0 >> 3) & 63;
            int nb = (g0 >> 9) & 3;
            int kt = g0 >> 11;
            int k = kt * 32 + (l >> 4) * 8 + j;
            int o = (nb >> 1) * 32 + 2 * (l & 15) + (nb & 1);
            float v0, v1;
            if (k < 800) { v0 = w2b[k * 64 + o]; v1 = w2b[(k + 1) * 64 + o]; }
            else         { v0 = b2b[(k - 800) * 64 + o]; v1 = b2b[(k - 799) * 64 + o]; }
            Bg[idx] = pk_bf16(v0, v1);
        }
    }
    // grid-stride maxabs (cart from pos, bitwise-same math as pool1's mean)
    float m = 0.f;
    for (int e = blk * 256 + t; e < E2P; e += gridDim.x * 256) {
        int s = ei2[e], d = ei2[E2P + e];
        f32x2 ps0 = ((const f32x2*)pos)[2 * s], ps1 = ((const f32x2*)pos)[2 * s + 1];
        f32x2 pd0 = ((const f32x2*)pos)[2 * d], pd1 = ((const f32x2*)pos)[2 * d + 1];
        float c0 = 0.5f * (ps0.x + ps1.x) - 0.5f * (pd0.x + pd1.x);
        float c1 = 0.5f * (ps0.y + ps1.y) - 0.5f * (pd0.y + pd1.y);
        m = fmaxf(m, fmaxf(fabsf(c0), fabsf(c1)));
    }
#pragma unroll
    for (int off = 32; off; off >>= 1)
        m = fmaxf(m, __shfl_down(m, off));
    if ((t & 63) == 0)
        atomicMax(maxbits, __float_as_uint(m));
}

// ---------------- conv1 via MFMA; epilogue = packed bf16 atomics, full 64B row/instr
__global__ __launch_bounds__(256) void conv1_kernel(
    const float* __restrict__ x, const float* __restrict__ ea,
    const int* __restrict__ ei,
    const float* __restrict__ w1, const float* __restrict__ b1,
    const unsigned int* __restrict__ W2f,
    unsigned short* __restrict__ agg1b)
{
    __shared__ unsigned int afrag[16][4][64];   // 16 KB
    __shared__ int dst_lds[256];

    int t = threadIdx.x;
    int e = blockIdx.x * 256 + t;               // E1 % 256 == 0
    f32x2 a = ((const f32x2*)ea)[e];
    int s = ei[e], d = ei[E1 + e];
    float xv = x[s];
    dst_lds[t] = d;

    float v[26];
#pragma unroll
    for (int h = 0; h < HIDN; ++h) {
        float u = fmaf(a.x, w1[h], fmaf(a.y, w1[HIDN + h], b1[h]));
        v[h] = fmaxf(u, 0.f) * xv;
    }
    v[25] = xv;

    int tile = t >> 4, r16 = t & 15;
#pragma unroll
    for (int p = 0; p < 13; ++p) {              // pair p covers k = 2p, 2p+1
        int g = p >> 2, j = p & 3;
        afrag[tile][j][g * 16 + r16] = pk_bf16(v[2 * p], v[2 * p + 1]);
    }
    afrag[tile][1][48 + r16] = 0;               // k = 26..31 zero
    afrag[tile][2][48 + r16] = 0;
    afrag[tile][3][48 + r16] = 0;
    __syncthreads();

    int lane = t & 63, wave = t >> 6;
    FragU bf0, bf1;
    bf0.i = *(const int4v*)(W2f + lane * 4);
    bf1.i = *(const int4v*)(W2f + (64 + lane) * 4);
    int c = lane & 15, rg = lane >> 4;

#pragma unroll
    for (int ti = 0; ti < 4; ++ti) {
        int tl = wave * 4 + ti;
        FragU af;
        af.i.x = afrag[tl][0][lane];
        af.i.y = afrag[tl][1][lane];
        af.i.z = afrag[tl][2][lane];
        af.i.w = afrag[tl][3][lane];
        f32x4 a0 = (f32x4){0.f, 0.f, 0.f, 0.f};
        f32x4 a1 = (f32x4){0.f, 0.f, 0.f, 0.f};
        a0 = __builtin_amdgcn_mfma_f32_16x16x32_bf16(af.s, bf0.s, a0, 0, 0, 0);
        a1 = __builtin_amdgcn_mfma_f32_16x16x32_bf16(af.s, bf1.s, a1, 0, 0, 0);
#pragma unroll
        for (int jj = 0; jj < 4; ++jj) {
            int le = tl * 16 + rg * 4 + jj;
            // lane c holds channels (2c, 2c+1) -> one pk atomic, rows fully covered
            atomic_pk_bf16(agg1b + (size_t)dst_lds[le] * C1 + 2 * c,
                           pk_bf16(a0[jj], a1[jj]));
        }
    }
}

// ---------------- finish conv1 (root+bias+elu) and pool1 (pairwise max)
__global__ __launch_bounds__(256) void pool1_kernel(
    const unsigned short* __restrict__ agg1b, const float* __restrict__ x,
    const float* __restrict__ root1, const float* __restrict__ bias1,
    unsigned short* __restrict__ x1b)
{
    int t = blockIdx.x * blockDim.x + threadIdx.x;
    if (t >= N1P * C1) return;
    int j = t >> 5, o = t & 31;
    int na = 2 * j, nb = 2 * j + 1;
    float r = root1[o], bo = bias1[o];
    float ha = elu1(bf2f(agg1b[(size_t)na * C1 + o]) + x[na] * r + bo);
    float hb = elu1(bf2f(agg1b[(size_t)nb * C1 + o]) + x[nb] * r + bo);
    float mx = fmaxf(ha, hb);
    x1b[t] = (unsigned short)(pk_bf16(mx, mx) & 0xffffu);
}

// ---------------- conv2 via MFMA: 128 edges/block, bf16 hid in LDS,
// software-prefetched B fragments, pk-bf16 atomic epilogue; cart from pos directly
__global__ __launch_bounds__(256) void conv2_kernel(
    const int* __restrict__ ei2, const float* __restrict__ pos,
    const unsigned short* __restrict__ x1b,
    const float* __restrict__ w1, const float* __restrict__ b1,
    const unsigned int* __restrict__ maxbits,
    const unsigned int* __restrict__ Bg,
    unsigned short* __restrict__ agg2b)
{
    __shared__ __align__(16) unsigned short xs_lds[128][40];  // 10.2 KB
    __shared__ unsigned int hidb[128][14];                     // 7.2 KB (13 pairs+pad)
    __shared__ int dst_lds[128];

    int t = threadIdx.x;
    int base = blockIdx.x * 128;

    if (t < 128) {   // stage one edge per thread
        int ge = base + t;
        bool ok = ge < E2P;
        float inv = 0.5f / __uint_as_float(maxbits[0]);
        int s = 0, d = 0;
        if (ok) { s = ei2[ge]; d = ei2[E2P + ge]; }
        dst_lds[t] = d;
        f32x2 ps0 = ((const f32x2*)pos)[2 * s], ps1 = ((const f32x2*)pos)[2 * s + 1];
        f32x2 pd0 = ((const f32x2*)pos)[2 * d], pd1 = ((const f32x2*)pos)[2 * d + 1];
        float a0 = (0.5f * (ps0.x + ps1.x) - 0.5f * (pd0.x + pd1.x)) * inv + 0.5f;
        float a1 = (0.5f * (ps0.y + ps1.y) - 0.5f * (pd0.y + pd1.y)) * inv + 0.5f;
        float hv[26];
#pragma unroll
        for (int h = 0; h < HIDN; ++h) {
            float u = fmaf(a0, w1[h], fmaf(a1, w1[HIDN + h], b1[h]));
            hv[h] = ok ? fmaxf(u, 0.f) : 0.f;
        }
        hv[25] = 0.f;
#pragma unroll
        for (int p = 0; p < 13; ++p)
            hidb[t][p] = pk_bf16(hv[2 * p], hv[2 * p + 1]);
        const int4v* xp = (const int4v*)(x1b + (size_t)s * C1);
#pragma unroll
        for (int q = 0; q < 4; ++q) {
            int4v z4 = (int4v){0, 0, 0, 0};
            *(int4v*)&xs_lds[t][q * 8] = ok ? xp[q] : z4;
        }
    }
    __syncthreads();

    int lane = t & 63, wave = t >> 6;
    int c = lane & 15, rg = lane >> 4;

    FragU xv2[2];
    float xfl[2][8];
#pragma unroll
    for (int ti = 0; ti < 2; ++ti) {
        int row = (wave * 2 + ti) * 16 + c;
        xv2[ti].i = *(const int4v*)&xs_lds[row][rg * 8];
#pragma unroll
        for (int g2 = 0; g2 < 4; ++g2) {
            unsigned int u = (unsigned int)xv2[ti].i[g2];
            xfl[ti][2 * g2]     = __uint_as_float(u << 16);
            xfl[ti][2 * g2 + 1] = __uint_as_float(u & 0xffff0000u);
        }
    }

    f32x4 acc[2][4];
#pragma unroll
    for (int ti = 0; ti < 2; ++ti)
#pragma unroll
        for (int nb = 0; nb < 4; ++nb)
            acc[ti][nb] = (f32x4){0.f, 0.f, 0.f, 0.f};

    const int4v* Bg4 = (const int4v*)Bg;
    FragU bf[4];
#pragma unroll
    for (int nb = 0; nb < 4; ++nb)
        bf[nb].i = Bg4[nb * 64 + lane];          // kt = 0

#pragma unroll
    for (int kt = 0; kt < 25; ++kt) {
        FragU bn[4];                             // prefetch kt+1 (kt=24 -> b2 frags)
#pragma unroll
        for (int nb = 0; nb < 4; ++nb)
            bn[nb].i = Bg4[((kt + 1) * 4 + nb) * 64 + lane];
#pragma unroll
        for (int ti = 0; ti < 2; ++ti) {
            unsigned int hu = hidb[(wave * 2 + ti) * 16 + c][kt >> 1];
            float hvv = bf2f((unsigned short)((kt & 1) ? (hu >> 16) : (hu & 0xffffu)));
            FragU af;
            af.i.x = pk_bf16(hvv * xfl[ti][0], hvv * xfl[ti][1]);
            af.i.y = pk_bf16(hvv * xfl[ti][2], hvv * xfl[ti][3]);
            af.i.z = pk_bf16(hvv * xfl[ti][4], hvv * xfl[ti][5]);
            af.i.w = pk_bf16(hvv * xfl[ti][6], hvv * xfl[ti][7]);
#pragma unroll
            for (int nb = 0; nb < 4; ++nb)
                acc[ti][nb] = __builtin_amdgcn_mfma_f32_16x16x32_bf16(af.s, bf[nb].s, acc[ti][nb], 0, 0, 0);
        }
#pragma unroll
        for (int nb = 0; nb < 4; ++nb) bf[nb] = bn[nb];
    }
    // kt = 25: b2 term, A = xs directly
#pragma unroll
    for (int ti = 0; ti < 2; ++ti)
#pragma unroll
        for (int nb = 0; nb < 4; ++nb)
            acc[ti][nb] = __builtin_amdgcn_mfma_f32_16x16x32_bf16(xv2[ti].s, bf[nb].s, acc[ti][nb], 0, 0, 0);

    // epilogue: lane c holds channels (2c,2c+1) [nb 0,1] and (32+2c,32+2c+1) [nb 2,3]
#pragma unroll
    for (int ti = 0; ti < 2; ++ti) {
        int tl = wave * 2 + ti;
#pragma unroll
        for (int jj = 0; jj < 4; ++jj) {
            int le = tl * 16 + rg * 4 + jj;
            if (base + le < E2P) {
                unsigned short* dp = agg2b + (size_t)dst_lds[le] * C2;
                atomic_pk_bf16(dp + 2 * c,      pk_bf16(acc[ti][0][jj], acc[ti][1][jj]));
                atomic_pk_bf16(dp + 32 + 2 * c, pk_bf16(acc[ti][2][jj], acc[ti][3][jj]));
            }
        }
    }
}

// ---------------- fused: finish conv2 (root2+bias2+elu), pool2 (pairwise max),
// per-graph mean, then FC head + log_softmax
__global__ __launch_bounds__(256) void pool2_head_kernel(
    const unsigned short* __restrict__ agg2b, const unsigned short* __restrict__ x1b,
    const float* __restrict__ root2, const float* __restrict__ bias2,
    const float* __restrict__ fc1w, const float* __restrict__ fc1b,
    const float* __restrict__ fc2w, const float* __restrict__ fc2b,
    float* __restrict__ out)
{
    int b = blockIdx.x;
    int t = threadIdx.x;
    int w = t >> 6, o = t & 63;
    __shared__ float part[4][C2];
    __shared__ float gs[C2];
    __shared__ float zs[128];
    __shared__ float ls[NCLS];

    // hoist root2 column o (reused for all 26 node evaluations per thread)
    float r2[C1];
#pragma unroll
    for (int i = 0; i < C1; ++i) r2[i] = root2[i * C2 + o];
    float bo = bias2[o];

    float sum = 0.f;
    for (int jj = w; jj < 50; jj += 4) {
        int j = b * 50 + jj;
        float hv[2];
#pragma unroll
        for (int tt = 0; tt < 2; ++tt) {
            int n = 2 * j + tt;
            float a = bf2f(agg2b[(size_t)n * C2 + o]) + bo;
            const int4v* xp = (const int4v*)(x1b + (size_t)n * C1);
#pragma unroll
            for (int q = 0; q < 4; ++q) {
                int4v v4 = xp[q];
#pragma unroll
                for (int g2 = 0; g2 < 4; ++g2) {
                    unsigned int u = (unsigned int)v4[g2];
                    a = fmaf(__uint_as_float(u << 16),         r2[q * 8 + 2 * g2],     a);
                    a = fmaf(__uint_as_float(u & 0xffff0000u), r2[q * 8 + 2 * g2 + 1], a);
                }
            }
            hv[tt] = elu1(a);
        }
        sum += fmaxf(hv[0], hv[1]);
    }
    part[w][o] = sum;
    __syncthreads();
    if (w == 0)
        gs[o] = (part[0][o] + part[1][o] + part[2][o] + part[3][o]) * (1.f / 50.f);
    __syncthreads();
    if (t < 128) {
        float z = fc1b[t];
#pragma unroll
        for (int i = 0; i < C2; ++i) z = fmaf(gs[i], fc1w[i * 128 + t], z);
        zs[t] = elu1(z);
    }
    __syncthreads();
    if (t < NCLS) {
        float l = fc2b[t];
#pragma unroll
        for (int k = 0; k < 128; ++k) l = fmaf(zs[k], fc2w[k * NCLS + t], l);
        ls[t] = l;
    }
    __syncthreads();
    if (t < NCLS) {
        float mx = ls[0];
#pragma unroll
        for (int cc = 1; cc < NCLS; ++cc) mx = fmaxf(mx, ls[cc]);
        float se = 0.f;
#pragma unroll
        for (int cc = 0; cc < NCLS; ++cc) se += expf(ls[cc] - mx);
        out[b * NCLS + t] = ls[t] - mx - logf(se);
    }
}

extern "C" void kernel_launch(void* const* d_in, const int* in_sizes, int n_in,
                              void* d_out, int out_size, void* d_ws, size_t ws_size,
                              hipStream_t stream)
{
    const float* x    = (const float*)d_in[0];
    const float* pos  = (const float*)d_in[1];
    const int*   ei   = (const int*)d_in[2];
    const float* ea   = (const float*)d_in[3];
    const int*   ei2  = (const int*)d_in[6];
    const float* n1w1 = (const float*)d_in[8];
    const float* n1b1 = (const float*)d_in[9];
    const float* n1w2 = (const float*)d_in[10];
    const float* n1b2 = (const float*)d_in[11];
    const float* root1= (const float*)d_in[12];
    const float* bias1= (const float*)d_in[13];
    const float* n2w1 = (const float*)d_in[14];
    const float* n2b1 = (const float*)d_in[15];
    const float* n2w2 = (const float*)d_in[16];
    const float* n2b2 = (const float*)d_in[17];
    const float* root2= (const float*)d_in[18];
    const float* bias2= (const float*)d_in[19];
    const float* fc1w = (const float*)d_in[20];
    const float* fc1b = (const float*)d_in[21];
    const float* fc2w = (const float*)d_in[22];
    const float* fc2b = (const float*)d_in[23];
    float* out = (float*)d_out;

    // zero region first (single memset): agg1b | agg2b | maxbits
    char* w = (char*)d_ws;
    unsigned short* agg1b = (unsigned short*)w;  w += (size_t)N_NODES * C1 * 2;   // 12.8 MB
    unsigned short* agg2b = (unsigned short*)w;  w += (size_t)N1P * C2 * 2;       // 12.8 MB
    unsigned int* maxbits = (unsigned int*)w;    w += 1024;
    size_t zero_bytes = (size_t)N_NODES * C1 * 2 + (size_t)N1P * C2 * 2 + 1024;
    unsigned short* x1b   = (unsigned short*)w;  w += (size_t)N1P * C1 * 2;       // 6.4 MB
    unsigned int* Bg = (unsigned int*)w;         w += 26624 * 4;
    unsigned int* W2f = (unsigned int*)w;        w += 512 * 4;

    hipMemsetAsync(agg1b, 0, zero_bytes, stream);

    bgbuild_kernel<<<106, 256, 0, stream>>>(n1w2, n1b2, n2w2, n2b2, pos, ei2,
                                            W2f, Bg, maxbits);
    conv1_kernel<<<E1 / 256, 256, 0, stream>>>(x, ea, ei, n1w1, n1b1, W2f, agg1b);
    pool1_kernel<<<(N1P * C1 + 255) / 256, 256, 0, stream>>>(agg1b, x, root1, bias1, x1b);
    conv2_kernel<<<(E2P + 127) / 128, 256, 0, stream>>>(ei2, pos, x1b, n2w1, n2b1, maxbits, Bg, agg2b);
    pool2_head_kernel<<<BGR, 256, 0, stream>>>(agg2b, x1b, root2, bias2,
                                               fc1w, fc1b, fc2w, fc2b, out);
}

// Round 13
// 159.703 us; speedup vs baseline: 1.1683x; 1.0353x over previous
//
#include <hip/hip_runtime.h>
#include <hip/hip_bf16.h>

#define N_NODES 200000
#define E1 1600000
#define N1P 100000
#define E2P 100000
#define N2P 50000
#define BGR 1000
#define C1 32
#define C2 64
#define HIDN 25
#define NCLS 10
#define POOL1_BLKS 12500          // N1P*C1/256 exact
#define BG_BLKS 104               // 26624/256 exact

typedef short short8 __attribute__((ext_vector_type(8)));
typedef int int4v __attribute__((ext_vector_type(4)));
typedef float f32x4 __attribute__((ext_vector_type(4)));
typedef float f32x2 __attribute__((ext_vector_type(2)));

union FragU { int4v i; short8 s; };

__device__ __forceinline__ float elu1(float v) {
    return v > 0.f ? v : expm1f(v);
}
__device__ __forceinline__ float bf2f(unsigned short u) {
    return __uint_as_float(((unsigned int)u) << 16);
}
__device__ __forceinline__ unsigned int pk_bf16(float a, float b) {
    unsigned int r;
    asm("v_cvt_pk_bf16_f32 %0, %1, %2" : "=v"(r) : "v"(a), "v"(b));
    return r;
}
__device__ __forceinline__ void atomic_pk_bf16(unsigned short* p, unsigned int pk) {
    asm volatile("global_atomic_pk_add_bf16 %0, %1, off" :: "v"(p), "v"(pk) : "memory");
}

// ---------------- conv1 via MFMA; W2f built per-block in LDS (removes bgbuild dep);
// epilogue = packed bf16 atomics, full 64B row/instr
__global__ __launch_bounds__(256) void conv1_kernel(
    const float* __restrict__ x, const float* __restrict__ ea,
    const int* __restrict__ ei,
    const float* __restrict__ w1, const float* __restrict__ b1,
    const float* __restrict__ w2a, const float* __restrict__ b2a,
    unsigned short* __restrict__ agg1b)
{
    __shared__ unsigned int afrag[16][4][64];   // 16 KB
    __shared__ int dst_lds[256];
    __shared__ unsigned int w2f[512];           // 2 KB: conv1 B-fragments

    int t = threadIdx.x;
    // build W2f (q = m*256 + l*4 + jj): thread t does q = t and q = t+256
#pragma unroll
    for (int half = 0; half < 2; ++half) {
        int q = half * 256 + t;
        int jj = q & 3, l = (q >> 2) & 63, m = q >> 8;
        int k0 = (l >> 4) * 8 + 2 * jj;
        int o = 2 * (l & 15) + m;               // even/odd channel perm
        float v0 = (k0 < 25) ? w2a[k0 * 32 + o] : (k0 == 25 ? b2a[o] : 0.f);
        int k1 = k0 + 1;
        float v1 = (k1 < 25) ? w2a[k1 * 32 + o] : (k1 == 25 ? b2a[o] : 0.f);
        w2f[q] = pk_bf16(v0, v1);
    }

    int e = blockIdx.x * 256 + t;               // E1 % 256 == 0
    f32x2 a = ((const f32x2*)ea)[e];
    int s = ei[e], d = ei[E1 + e];
    float xv = x[s];
    dst_lds[t] = d;

    float v[26];
#pragma unroll
    for (int h = 0; h < HIDN; ++h) {
        float u = fmaf(a.x, w1[h], fmaf(a.y, w1[HIDN + h], b1[h]));
        v[h] = fmaxf(u, 0.f) * xv;
    }
    v[25] = xv;

    int tile = t >> 4, r16 = t & 15;
#pragma unroll
    for (int p = 0; p < 13; ++p) {              // pair p covers k = 2p, 2p+1
        int g = p >> 2, j = p & 3;
        afrag[tile][j][g * 16 + r16] = pk_bf16(v[2 * p], v[2 * p + 1]);
    }
    afrag[tile][1][48 + r16] = 0;               // k = 26..31 zero
    afrag[tile][2][48 + r16] = 0;
    afrag[tile][3][48 + r16] = 0;
    __syncthreads();

    int lane = t & 63, wave = t >> 6;
    FragU bf0, bf1;
    bf0.i = *(const int4v*)(w2f + lane * 4);
    bf1.i = *(const int4v*)(w2f + (64 + lane) * 4);
    int c = lane & 15, rg = lane >> 4;

#pragma unroll
    for (int ti = 0; ti < 4; ++ti) {
        int tl = wave * 4 + ti;
        FragU af;
        af.i.x = afrag[tl][0][lane];
        af.i.y = afrag[tl][1][lane];
        af.i.z = afrag[tl][2][lane];
        af.i.w = afrag[tl][3][lane];
        f32x4 a0 = (f32x4){0.f, 0.f, 0.f, 0.f};
        f32x4 a1 = (f32x4){0.f, 0.f, 0.f, 0.f};
        a0 = __builtin_amdgcn_mfma_f32_16x16x32_bf16(af.s, bf0.s, a0, 0, 0, 0);
        a1 = __builtin_amdgcn_mfma_f32_16x16x32_bf16(af.s, bf1.s, a1, 0, 0, 0);
#pragma unroll
        for (int jj = 0; jj < 4; ++jj) {
            int le = tl * 16 + rg * 4 + jj;
            // lane c holds channels (2c, 2c+1) -> one pk atomic, rows fully covered
            atomic_pk_bf16(agg1b + (size_t)dst_lds[le] * C1 + 2 * c,
                           pk_bf16(a0[jj], a1[jj]));
        }
    }
}

// ---------------- pool1 (finish conv1: root+bias+elu, pairwise max) with tail
// blocks doing conv2 Bg build + global max|cart| (from pos directly)
__global__ __launch_bounds__(256) void pool1_kernel(
    const unsigned short* __restrict__ agg1b, const float* __restrict__ x,
    const float* __restrict__ root1, const float* __restrict__ bias1,
    unsigned short* __restrict__ x1b,
    const float* __restrict__ w2b, const float* __restrict__ b2b,
    const float* __restrict__ pos, const int* __restrict__ ei2,
    unsigned int* __restrict__ Bg, unsigned int* __restrict__ maxbits)
{
    int bid = blockIdx.x;
    int t = threadIdx.x;
    if (bid >= POOL1_BLKS) {
        int blk2 = bid - POOL1_BLKS;            // 0..103
        {   // conv2 B fragments: 26624 pairs = 104*256 exact
            int idx = blk2 * 256 + t;
            int g0 = idx * 2;
            int j = g0 & 7;
            int l = (g0 >> 3) & 63;
            int nb = (g0 >> 9) & 3;
            int kt = g0 >> 11;
            int k = kt * 32 + (l >> 4) * 8 + j;
            int o = (nb >> 1) * 32 + 2 * (l & 15) + (nb & 1);
            float v0, v1;
            if (k < 800) { v0 = w2b[k * 64 + o]; v1 = w2b[(k + 1) * 64 + o]; }
            else         { v0 = b2b[(k - 800) * 64 + o]; v1 = b2b[(k - 799) * 64 + o]; }
            Bg[idx] = pk_bf16(v0, v1);
        }
        // grid-stride maxabs (cart from pos, bitwise-same math as pool1's mean)
        float m = 0.f;
        for (int e = blk2 * 256 + t; e < E2P; e += BG_BLKS * 256) {
            int s = ei2[e], d = ei2[E2P + e];
            f32x2 ps0 = ((const f32x2*)pos)[2 * s], ps1 = ((const f32x2*)pos)[2 * s + 1];
            f32x2 pd0 = ((const f32x2*)pos)[2 * d], pd1 = ((const f32x2*)pos)[2 * d + 1];
            float c0 = 0.5f * (ps0.x + ps1.x) - 0.5f * (pd0.x + pd1.x);
            float c1 = 0.5f * (ps0.y + ps1.y) - 0.5f * (pd0.y + pd1.y);
            m = fmaxf(m, fmaxf(fabsf(c0), fabsf(c1)));
        }
#pragma unroll
        for (int off = 32; off; off >>= 1)
            m = fmaxf(m, __shfl_down(m, off));
        if ((t & 63) == 0)
            atomicMax(maxbits, __float_as_uint(m));
        return;
    }
    int tt = bid * 256 + t;                     // < N1P*C1 exact
    int j = tt >> 5, o = tt & 31;
    int na = 2 * j, nb = 2 * j + 1;
    float r = root1[o], bo = bias1[o];
    float ha = elu1(bf2f(agg1b[(size_t)na * C1 + o]) + x[na] * r + bo);
    float hb = elu1(bf2f(agg1b[(size_t)nb * C1 + o]) + x[nb] * r + bo);
    float mx = fmaxf(ha, hb);
    x1b[tt] = (unsigned short)(pk_bf16(mx, mx) & 0xffffu);
}

// ---------------- conv2 via MFMA: 256 edges/block, 256 thr (4 tiles/wave, r5
// structure), bf16 hid in LDS, B-prefetch, pk-bf16 atomic epilogue
__global__ __launch_bounds__(256) void conv2_kernel(
    const int* __restrict__ ei2, const float* __restrict__ pos,
    const unsigned short* __restrict__ x1b,
    const float* __restrict__ w1, const float* __restrict__ b1,
    const unsigned int* __restrict__ maxbits,
    const unsigned int* __restrict__ Bg,
    unsigned short* __restrict__ agg2b)
{
    __shared__ __align__(16) unsigned short xs_lds[256][40];  // 20 KB
    __shared__ unsigned int hidb[256][14];                     // 14.3 KB
    __shared__ int dst_lds[256];

    int t = threadIdx.x;
    int base = blockIdx.x * 256;

    {   // stage one edge per thread
        int ge = base + t;
        bool ok = ge < E2P;
        float inv = 0.5f / __uint_as_float(maxbits[0]);
        int s = 0, d = 0;
        if (ok) { s = ei2[ge]; d = ei2[E2P + ge]; }
        dst_lds[t] = d;
        f32x2 ps0 = ((const f32x2*)pos)[2 * s], ps1 = ((const f32x2*)pos)[2 * s + 1];
        f32x2 pd0 = ((const f32x2*)pos)[2 * d], pd1 = ((const f32x2*)pos)[2 * d + 1];
        float a0 = (0.5f * (ps0.x + ps1.x) - 0.5f * (pd0.x + pd1.x)) * inv + 0.5f;
        float a1 = (0.5f * (ps0.y + ps1.y) - 0.5f * (pd0.y + pd1.y)) * inv + 0.5f;
        float hv[26];
#pragma unroll
        for (int h = 0; h < HIDN; ++h) {
            float u = fmaf(a0, w1[h], fmaf(a1, w1[HIDN + h], b1[h]));
            hv[h] = ok ? fmaxf(u, 0.f) : 0.f;
        }
        hv[25] = 0.f;
#pragma unroll
        for (int p = 0; p < 13; ++p)
            hidb[t][p] = pk_bf16(hv[2 * p], hv[2 * p + 1]);
        const int4v* xp = (const int4v*)(x1b + (size_t)s * C1);
#pragma unroll
        for (int q = 0; q < 4; ++q) {
            int4v z4 = (int4v){0, 0, 0, 0};
            *(int4v*)&xs_lds[t][q * 8] = ok ? xp[q] : z4;
        }
    }
    __syncthreads();

    int lane = t & 63, wave = t >> 6;
    int c = lane & 15, rg = lane >> 4;

    FragU xv4[4];
    float xfl[4][8];
#pragma unroll
    for (int ti = 0; ti < 4; ++ti) {
        int row = (wave * 4 + ti) * 16 + c;
        xv4[ti].i = *(const int4v*)&xs_lds[row][rg * 8];
#pragma unroll
        for (int g2 = 0; g2 < 4; ++g2) {
            unsigned int u = (unsigned int)xv4[ti].i[g2];
            xfl[ti][2 * g2]     = __uint_as_float(u << 16);
            xfl[ti][2 * g2 + 1] = __uint_as_float(u & 0xffff0000u);
        }
    }

    f32x4 acc[4][4];
#pragma unroll
    for (int ti = 0; ti < 4; ++ti)
#pragma unroll
        for (int nb = 0; nb < 4; ++nb)
            acc[ti][nb] = (f32x4){0.f, 0.f, 0.f, 0.f};

    const int4v* Bg4 = (const int4v*)Bg;
    FragU bf[4];
#pragma unroll
    for (int nb = 0; nb < 4; ++nb)
        bf[nb].i = Bg4[nb * 64 + lane];          // kt = 0

#pragma unroll 1
    for (int kt = 0; kt < 25; ++kt) {
        FragU bn[4];                             // prefetch kt+1 (kt=24 -> b2 frags)
#pragma unroll
        for (int nb = 0; nb < 4; ++nb)
            bn[nb].i = Bg4[((kt + 1) * 4 + nb) * 64 + lane];
#pragma unroll
        for (int ti = 0; ti < 4; ++ti) {
            unsigned int hu = hidb[(wave * 4 + ti) * 16 + c][kt >> 1];
            float hvv = bf2f((unsigned short)((kt & 1) ? (hu >> 16) : (hu & 0xffffu)));
            FragU af;
            af.i.x = pk_bf16(hvv * xfl[ti][0], hvv * xfl[ti][1]);
            af.i.y = pk_bf16(hvv * xfl[ti][2], hvv * xfl[ti][3]);
            af.i.z = pk_bf16(hvv * xfl[ti][4], hvv * xfl[ti][5]);
            af.i.w = pk_bf16(hvv * xfl[ti][6], hvv * xfl[ti][7]);
#pragma unroll
            for (int nb = 0; nb < 4; ++nb)
                acc[ti][nb] = __builtin_amdgcn_mfma_f32_16x16x32_bf16(af.s, bf[nb].s, acc[ti][nb], 0, 0, 0);
        }
#pragma unroll
        for (int nb = 0; nb < 4; ++nb) bf[nb] = bn[nb];
    }
    // kt = 25: b2 term, A = xs directly
#pragma unroll
    for (int ti = 0; ti < 4; ++ti)
#pragma unroll
        for (int nb = 0; nb < 4; ++nb)
            acc[ti][nb] = __builtin_amdgcn_mfma_f32_16x16x32_bf16(xv4[ti].s, bf[nb].s, acc[ti][nb], 0, 0, 0);

    // epilogue: lane c holds channels (2c,2c+1) [nb 0,1] and (32+2c,32+2c+1) [nb 2,3]
#pragma unroll
    for (int ti = 0; ti < 4; ++ti) {
        int tl = wave * 4 + ti;
#pragma unroll
        for (int jj = 0; jj < 4; ++jj) {
            int le = tl * 16 + rg * 4 + jj;
            if (base + le < E2P) {
                unsigned short* dp = agg2b + (size_t)dst_lds[le] * C2;
                atomic_pk_bf16(dp + 2 * c,      pk_bf16(acc[ti][0][jj], acc[ti][1][jj]));
                atomic_pk_bf16(dp + 32 + 2 * c, pk_bf16(acc[ti][2][jj], acc[ti][3][jj]));
            }
        }
    }
}

// ---------------- fused: finish conv2 (root2+bias2+elu), pool2 (pairwise max),
// per-graph mean, then FC head + log_softmax
__global__ __launch_bounds__(256) void pool2_head_kernel(
    const unsigned short* __restrict__ agg2b, const unsigned short* __restrict__ x1b,
    const float* __restrict__ root2, const float* __restrict__ bias2,
    const float* __restrict__ fc1w, const float* __restrict__ fc1b,
    const float* __restrict__ fc2w, const float* __restrict__ fc2b,
    float* __restrict__ out)
{
    int b = blockIdx.x;
    int t = threadIdx.x;
    int w = t >> 6, o = t & 63;
    __shared__ float part[4][C2];
    __shared__ float gs[C2];
    __shared__ float zs[128];
    __shared__ float ls[NCLS];

    // hoist root2 column o (reused for all 26 node evaluations per thread)
    float r2[C1];
#pragma unroll
    for (int i = 0; i < C1; ++i) r2[i] = root2[i * C2 + o];
    float bo = bias2[o];

    float sum = 0.f;
    for (int jj = w; jj < 50; jj += 4) {
        int j = b * 50 + jj;
        float hv[2];
#pragma unroll
        for (int tt = 0; tt < 2; ++tt) {
            int n = 2 * j + tt;
            float a = bf2f(agg2b[(size_t)n * C2 + o]) + bo;
            const int4v* xp = (const int4v*)(x1b + (size_t)n * C1);
#pragma unroll
            for (int q = 0; q < 4; ++q) {
                int4v v4 = xp[q];
#pragma unroll
                for (int g2 = 0; g2 < 4; ++g2) {
                    unsigned int u = (unsigned int)v4[g2];
                    a = fmaf(__uint_as_float(u << 16),         r2[q * 8 + 2 * g2],     a);
                    a = fmaf(__uint_as_float(u & 0xffff0000u), r2[q * 8 + 2 * g2 + 1], a);
                }
            }
            hv[tt] = elu1(a);
        }
        sum += fmaxf(hv[0], hv[1]);
    }
    part[w][o] = sum;
    __syncthreads();
    if (w == 0)
        gs[o] = (part[0][o] + part[1][o] + part[2][o] + part[3][o]) * (1.f / 50.f);
    __syncthreads();
    if (t < 128) {
        float z = fc1b[t];
#pragma unroll
        for (int i = 0; i < C2; ++i) z = fmaf(gs[i], fc1w[i * 128 + t], z);
        zs[t] = elu1(z);
    }
    __syncthreads();
    if (t < NCLS) {
        float l = fc2b[t];
#pragma unroll
        for (int k = 0; k < 128; ++k) l = fmaf(zs[k], fc2w[k * NCLS + t], l);
        ls[t] = l;
    }
    __syncthreads();
    if (t < NCLS) {
        float mx = ls[0];
#pragma unroll
        for (int cc = 1; cc < NCLS; ++cc) mx = fmaxf(mx, ls[cc]);
        float se = 0.f;
#pragma unroll
        for (int cc = 0; cc < NCLS; ++cc) se += expf(ls[cc] - mx);
        out[b * NCLS + t] = ls[t] - mx - logf(se);
    }
}

extern "C" void kernel_launch(void* const* d_in, const int* in_sizes, int n_in,
                              void* d_out, int out_size, void* d_ws, size_t ws_size,
                              hipStream_t stream)
{
    const float* x    = (const float*)d_in[0];
    const float* pos  = (const float*)d_in[1];
    const int*   ei   = (const int*)d_in[2];
    const float* ea   = (const float*)d_in[3];
    const int*   ei2  = (const int*)d_in[6];
    const float* n1w1 = (const float*)d_in[8];
    const float* n1b1 = (const float*)d_in[9];
    const float* n1w2 = (const float*)d_in[10];
    const float* n1b2 = (const float*)d_in[11];
    const float* root1= (const float*)d_in[12];
    const float* bias1= (const float*)d_in[13];
    const float* n2w1 = (const float*)d_in[14];
    const float* n2b1 = (const float*)d_in[15];
    const float* n2w2 = (const float*)d_in[16];
    const float* n2b2 = (const float*)d_in[17];
    const float* root2= (const float*)d_in[18];
    const float* bias2= (const float*)d_in[19];
    const float* fc1w = (const float*)d_in[20];
    const float* fc1b = (const float*)d_in[21];
    const float* fc2w = (const float*)d_in[22];
    const float* fc2b = (const float*)d_in[23];
    float* out = (float*)d_out;

    // zero region first (single memset): agg1b | agg2b | maxbits
    char* w = (char*)d_ws;
    unsigned short* agg1b = (unsigned short*)w;  w += (size_t)N_NODES * C1 * 2;   // 12.8 MB
    unsigned short* agg2b = (unsigned short*)w;  w += (size_t)N1P * C2 * 2;       // 12.8 MB
    unsigned int* maxbits = (unsigned int*)w;    w += 1024;
    size_t zero_bytes = (size_t)N_NODES * C1 * 2 + (size_t)N1P * C2 * 2 + 1024;
    unsigned short* x1b   = (unsigned short*)w;  w += (size_t)N1P * C1 * 2;       // 6.4 MB
    unsigned int* Bg = (unsigned int*)w;         w += 26624 * 4;

    hipMemsetAsync(agg1b, 0, zero_bytes, stream);

    conv1_kernel<<<E1 / 256, 256, 0, stream>>>(x, ea, ei, n1w1, n1b1, n1w2, n1b2, agg1b);
    pool1_kernel<<<POOL1_BLKS + BG_BLKS, 256, 0, stream>>>(agg1b, x, root1, bias1, x1b,
                                                           n2w2, n2b2, pos, ei2, Bg, maxbits);
    conv2_kernel<<<(E2P + 255) / 256, 256, 0, stream>>>(ei2, pos, x1b, n2w1, n2b1, maxbits, Bg, agg2b);
    pool2_head_kernel<<<BGR, 256, 0, stream>>>(agg2b, x1b, root2, bias2,
                                               fc1w, fc1b, fc2w, fc2b, out);
}

// Round 14
// 159.362 us; speedup vs baseline: 1.1708x; 1.0021x over previous
//
#include <hip/hip_runtime.h>
#include <hip/hip_bf16.h>

#define N_NODES 200000
#define E1 1600000
#define N1P 100000
#define E2P 100000
#define N2P 50000
#define BGR 1000
#define C1 32
#define C2 64
#define HIDN 25
#define NCLS 10
#define CONV1_BLKS 6250           // E1/256 exact
#define BG_BLKS 104               // 26624/256 exact

typedef short short8 __attribute__((ext_vector_type(8)));
typedef int int4v __attribute__((ext_vector_type(4)));
typedef float f32x4 __attribute__((ext_vector_type(4)));
typedef float f32x2 __attribute__((ext_vector_type(2)));

union FragU { int4v i; short8 s; };

__device__ __forceinline__ float elu1(float v) {
    return v > 0.f ? v : expm1f(v);
}
__device__ __forceinline__ float bf2f(unsigned short u) {
    return __uint_as_float(((unsigned int)u) << 16);
}
__device__ __forceinline__ unsigned int pk_bf16(float a, float b) {
    unsigned int r;
    asm("v_cvt_pk_bf16_f32 %0, %1, %2" : "=v"(r) : "v"(a), "v"(b));
    return r;
}
__device__ __forceinline__ void atomic_pk_bf16(unsigned short* p, unsigned int pk) {
    asm volatile("global_atomic_pk_add_bf16 %0, %1, off" :: "v"(p), "v"(pk) : "memory");
}

// ---------------- conv1 via MFMA (W2f built per-block in LDS); tail blocks build
// conv2 Bg fragments + global max|cart| (no agg1b dependency)
__global__ __launch_bounds__(256) void conv1_kernel(
    const float* __restrict__ x, const float* __restrict__ ea,
    const int* __restrict__ ei,
    const float* __restrict__ w1, const float* __restrict__ b1,
    const float* __restrict__ w2a, const float* __restrict__ b2a,
    const float* __restrict__ w2b, const float* __restrict__ b2b,
    const float* __restrict__ pos, const int* __restrict__ ei2,
    unsigned int* __restrict__ Bg, unsigned int* __restrict__ maxbits,
    unsigned short* __restrict__ agg1b)
{
    __shared__ unsigned int afrag[16][4][64];   // 16 KB
    __shared__ int dst_lds[256];
    __shared__ unsigned int w2f[512];           // 2 KB: conv1 B-fragments

    int bid = blockIdx.x;
    int t = threadIdx.x;

    if (bid >= CONV1_BLKS) {                    // tail: Bg build + maxabs
        int blk2 = bid - CONV1_BLKS;            // 0..103
        {   // conv2 B fragments: 26624 pairs = 104*256 exact
            int idx = blk2 * 256 + t;
            int g0 = idx * 2;
            int j = g0 & 7;
            int l = (g0 >> 3) & 63;
            int nb = (g0 >> 9) & 3;
            int kt = g0 >> 11;
            int k = kt * 32 + (l >> 4) * 8 + j;
            int o = (nb >> 1) * 32 + 2 * (l & 15) + (nb & 1);
            float v0, v1;
            if (k < 800) { v0 = w2b[k * 64 + o]; v1 = w2b[(k + 1) * 64 + o]; }
            else         { v0 = b2b[(k - 800) * 64 + o]; v1 = b2b[(k - 799) * 64 + o]; }
            Bg[idx] = pk_bf16(v0, v1);
        }
        float m = 0.f;
        for (int e = blk2 * 256 + t; e < E2P; e += BG_BLKS * 256) {
            int s = ei2[e], d = ei2[E2P + e];
            f32x2 ps0 = ((const f32x2*)pos)[2 * s], ps1 = ((const f32x2*)pos)[2 * s + 1];
            f32x2 pd0 = ((const f32x2*)pos)[2 * d], pd1 = ((const f32x2*)pos)[2 * d + 1];
            float c0 = 0.5f * (ps0.x + ps1.x) - 0.5f * (pd0.x + pd1.x);
            float c1 = 0.5f * (ps0.y + ps1.y) - 0.5f * (pd0.y + pd1.y);
            m = fmaxf(m, fmaxf(fabsf(c0), fabsf(c1)));
        }
#pragma unroll
        for (int off = 32; off; off >>= 1)
            m = fmaxf(m, __shfl_down(m, off));
        if ((t & 63) == 0)
            atomicMax(maxbits, __float_as_uint(m));
        return;
    }

    // build W2f (q = m*256 + l*4 + jj): thread t does q = t and q = t+256
#pragma unroll
    for (int half = 0; half < 2; ++half) {
        int q = half * 256 + t;
        int jj = q & 3, l = (q >> 2) & 63, m = q >> 8;
        int k0 = (l >> 4) * 8 + 2 * jj;
        int o = 2 * (l & 15) + m;               // even/odd channel perm
        float v0 = (k0 < 25) ? w2a[k0 * 32 + o] : (k0 == 25 ? b2a[o] : 0.f);
        int k1 = k0 + 1;
        float v1 = (k1 < 25) ? w2a[k1 * 32 + o] : (k1 == 25 ? b2a[o] : 0.f);
        w2f[q] = pk_bf16(v0, v1);
    }

    int e = bid * 256 + t;                      // E1 % 256 == 0
    f32x2 a = ((const f32x2*)ea)[e];
    int s = ei[e], d = ei[E1 + e];
    float xv = x[s];
    dst_lds[t] = d;

    float v[26];
#pragma unroll
    for (int h = 0; h < HIDN; ++h) {
        float u = fmaf(a.x, w1[h], fmaf(a.y, w1[HIDN + h], b1[h]));
        v[h] = fmaxf(u, 0.f) * xv;
    }
    v[25] = xv;

    int tile = t >> 4, r16 = t & 15;
#pragma unroll
    for (int p = 0; p < 13; ++p) {              // pair p covers k = 2p, 2p+1
        int g = p >> 2, j = p & 3;
        afrag[tile][j][g * 16 + r16] = pk_bf16(v[2 * p], v[2 * p + 1]);
    }
    afrag[tile][1][48 + r16] = 0;               // k = 26..31 zero
    afrag[tile][2][48 + r16] = 0;
    afrag[tile][3][48 + r16] = 0;
    __syncthreads();

    int lane = t & 63, wave = t >> 6;
    FragU bf0, bf1;
    bf0.i = *(const int4v*)(w2f + lane * 4);
    bf1.i = *(const int4v*)(w2f + (64 + lane) * 4);
    int c = lane & 15, rg = lane >> 4;

#pragma unroll
    for (int ti = 0; ti < 4; ++ti) {
        int tl = wave * 4 + ti;
        FragU af;
        af.i.x = afrag[tl][0][lane];
        af.i.y = afrag[tl][1][lane];
        af.i.z = afrag[tl][2][lane];
        af.i.w = afrag[tl][3][lane];
        f32x4 a0 = (f32x4){0.f, 0.f, 0.f, 0.f};
        f32x4 a1 = (f32x4){0.f, 0.f, 0.f, 0.f};
        a0 = __builtin_amdgcn_mfma_f32_16x16x32_bf16(af.s, bf0.s, a0, 0, 0, 0);
        a1 = __builtin_amdgcn_mfma_f32_16x16x32_bf16(af.s, bf1.s, a1, 0, 0, 0);
#pragma unroll
        for (int jj = 0; jj < 4; ++jj) {
            int le = tl * 16 + rg * 4 + jj;
            // lane c holds channels (2c, 2c+1) -> one pk atomic, rows fully covered
            atomic_pk_bf16(agg1b + (size_t)dst_lds[le] * C1 + 2 * c,
                           pk_bf16(a0[jj], a1[jj]));
        }
    }
}

// ---------------- conv2 via MFMA: 256 edges/block; x1[src] computed ON THE FLY
// from agg1b (pool1 eliminated); bf16 hid in LDS, B-prefetch, pk-bf16 epilogue
__global__ __launch_bounds__(256) void conv2_kernel(
    const int* __restrict__ ei2, const float* __restrict__ pos,
    const unsigned short* __restrict__ agg1b, const float* __restrict__ x,
    const float* __restrict__ root1, const float* __restrict__ bias1,
    const float* __restrict__ w1, const float* __restrict__ b1,
    const unsigned int* __restrict__ maxbits,
    const unsigned int* __restrict__ Bg,
    unsigned short* __restrict__ agg2b)
{
    __shared__ __align__(16) unsigned short xs_lds[256][40];  // 20 KB
    __shared__ unsigned int hidb[256][14];                     // 14.3 KB
    __shared__ int dst_lds[256];

    int t = threadIdx.x;
    int base = blockIdx.x * 256;

    {   // stage one edge per thread: hid[25] + on-the-fly x1[src] row (bitwise = pool1)
        int ge = base + t;
        bool ok = ge < E2P;
        float inv = 0.5f / __uint_as_float(maxbits[0]);
        int s = 0, d = 0;
        if (ok) { s = ei2[ge]; d = ei2[E2P + ge]; }
        dst_lds[t] = d;
        f32x2 ps0 = ((const f32x2*)pos)[2 * s], ps1 = ((const f32x2*)pos)[2 * s + 1];
        f32x2 pd0 = ((const f32x2*)pos)[2 * d], pd1 = ((const f32x2*)pos)[2 * d + 1];
        float a0 = (0.5f * (ps0.x + ps1.x) - 0.5f * (pd0.x + pd1.x)) * inv + 0.5f;
        float a1 = (0.5f * (ps0.y + ps1.y) - 0.5f * (pd0.y + pd1.y)) * inv + 0.5f;
        float hv[26];
#pragma unroll
        for (int h = 0; h < HIDN; ++h) {
            float u = fmaf(a0, w1[h], fmaf(a1, w1[HIDN + h], b1[h]));
            hv[h] = ok ? fmaxf(u, 0.f) : 0.f;
        }
        hv[25] = 0.f;
#pragma unroll
        for (int p = 0; p < 13; ++p)
            hidb[t][p] = pk_bf16(hv[2 * p], hv[2 * p + 1]);

        const int4v* ga = (const int4v*)(agg1b + (size_t)(2 * s) * C1);
        const int4v* gb = (const int4v*)(agg1b + (size_t)(2 * s + 1) * C1);
        float xa = x[2 * s], xb = x[2 * s + 1];
#pragma unroll
        for (int q = 0; q < 4; ++q) {
            int4v va = ga[q], vb = gb[q];
            int4v pkt;
#pragma unroll
            for (int g2 = 0; g2 < 4; ++g2) {
                unsigned int ua = (unsigned int)va[g2], ub = (unsigned int)vb[g2];
                int ch = q * 8 + 2 * g2;
                float r0 = root1[ch], r1v = root1[ch + 1];
                float bb0 = bias1[ch], bb1 = bias1[ch + 1];
                float v0 = fmaxf(elu1(__uint_as_float(ua << 16) + xa * r0 + bb0),
                                 elu1(__uint_as_float(ub << 16) + xb * r0 + bb0));
                float v1 = fmaxf(elu1(__uint_as_float(ua & 0xffff0000u) + xa * r1v + bb1),
                                 elu1(__uint_as_float(ub & 0xffff0000u) + xb * r1v + bb1));
                pkt[g2] = (int)pk_bf16(v0, v1);
            }
            int4v z4 = (int4v){0, 0, 0, 0};
            *(int4v*)&xs_lds[t][q * 8] = ok ? pkt : z4;
        }
    }
    __syncthreads();

    int lane = t & 63, wave = t >> 6;
    int c = lane & 15, rg = lane >> 4;

    FragU xv4[4];
    float xfl[4][8];
#pragma unroll
    for (int ti = 0; ti < 4; ++ti) {
        int row = (wave * 4 + ti) * 16 + c;
        xv4[ti].i = *(const int4v*)&xs_lds[row][rg * 8];
#pragma unroll
        for (int g2 = 0; g2 < 4; ++g2) {
            unsigned int u = (unsigned int)xv4[ti].i[g2];
            xfl[ti][2 * g2]     = __uint_as_float(u << 16);
            xfl[ti][2 * g2 + 1] = __uint_as_float(u & 0xffff0000u);
        }
    }

    f32x4 acc[4][4];
#pragma unroll
    for (int ti = 0; ti < 4; ++ti)
#pragma unroll
        for (int nb = 0; nb < 4; ++nb)
            acc[ti][nb] = (f32x4){0.f, 0.f, 0.f, 0.f};

    const int4v* Bg4 = (const int4v*)Bg;
    FragU bf[4];
#pragma unroll
    for (int nb = 0; nb < 4; ++nb)
        bf[nb].i = Bg4[nb * 64 + lane];          // kt = 0

#pragma unroll 1
    for (int kt = 0; kt < 25; ++kt) {
        FragU bn[4];                             // prefetch kt+1 (kt=24 -> b2 frags)
#pragma unroll
        for (int nb = 0; nb < 4; ++nb)
            bn[nb].i = Bg4[((kt + 1) * 4 + nb) * 64 + lane];
#pragma unroll
        for (int ti = 0; ti < 4; ++ti) {
            unsigned int hu = hidb[(wave * 4 + ti) * 16 + c][kt >> 1];
            float hvv = bf2f((unsigned short)((kt & 1) ? (hu >> 16) : (hu & 0xffffu)));
            FragU af;
            af.i.x = pk_bf16(hvv * xfl[ti][0], hvv * xfl[ti][1]);
            af.i.y = pk_bf16(hvv * xfl[ti][2], hvv * xfl[ti][3]);
            af.i.z = pk_bf16(hvv * xfl[ti][4], hvv * xfl[ti][5]);
            af.i.w = pk_bf16(hvv * xfl[ti][6], hvv * xfl[ti][7]);
#pragma unroll
            for (int nb = 0; nb < 4; ++nb)
                acc[ti][nb] = __builtin_amdgcn_mfma_f32_16x16x32_bf16(af.s, bf[nb].s, acc[ti][nb], 0, 0, 0);
        }
#pragma unroll
        for (int nb = 0; nb < 4; ++nb) bf[nb] = bn[nb];
    }
    // kt = 25: b2 term, A = xs directly
#pragma unroll
    for (int ti = 0; ti < 4; ++ti)
#pragma unroll
        for (int nb = 0; nb < 4; ++nb)
            acc[ti][nb] = __builtin_amdgcn_mfma_f32_16x16x32_bf16(xv4[ti].s, bf[nb].s, acc[ti][nb], 0, 0, 0);

    // epilogue: lane c holds channels (2c,2c+1) [nb 0,1] and (32+2c,32+2c+1) [nb 2,3]
#pragma unroll
    for (int ti = 0; ti < 4; ++ti) {
        int tl = wave * 4 + ti;
#pragma unroll
        for (int jj = 0; jj < 4; ++jj) {
            int le = tl * 16 + rg * 4 + jj;
            if (base + le < E2P) {
                unsigned short* dp = agg2b + (size_t)dst_lds[le] * C2;
                atomic_pk_bf16(dp + 2 * c,      pk_bf16(acc[ti][0][jj], acc[ti][1][jj]));
                atomic_pk_bf16(dp + 32 + 2 * c, pk_bf16(acc[ti][2][jj], acc[ti][3][jj]));
            }
        }
    }
}

// ---------------- fused: finish conv2 (root2+bias2+elu), pool2 (pairwise max),
// per-graph mean, FC head + log_softmax; x1 rows staged on the fly from agg1b
__global__ __launch_bounds__(256) void pool2_head_kernel(
    const unsigned short* __restrict__ agg2b,
    const unsigned short* __restrict__ agg1b, const float* __restrict__ x,
    const float* __restrict__ root1, const float* __restrict__ bias1,
    const float* __restrict__ root2, const float* __restrict__ bias2,
    const float* __restrict__ fc1w, const float* __restrict__ fc1b,
    const float* __restrict__ fc2w, const float* __restrict__ fc2b,
    float* __restrict__ out)
{
    int b = blockIdx.x;
    int t = threadIdx.x;
    int w = t >> 6, o = t & 63;
    __shared__ float part[4][C2];
    __shared__ float gs[C2];
    __shared__ float zs[128];
    __shared__ float ls[NCLS];
    __shared__ __align__(16) unsigned int x1_lds[100][16];   // 6.4 KB

    // stage x1 rows for this graph's 100 N1P-level nodes (bitwise = old pool1)
    for (int it = t; it < 1600; it += 256) {
        int ln = it >> 4, q = it & 15;          // q covers channels 2q, 2q+1
        int n = b * 100 + ln;
        unsigned int ua = *(const unsigned int*)(agg1b + (size_t)(2 * n) * C1 + 2 * q);
        unsigned int ub = *(const unsigned int*)(agg1b + (size_t)(2 * n + 1) * C1 + 2 * q);
        float xa = x[2 * n], xb = x[2 * n + 1];
        float r0 = root1[2 * q], r1v = root1[2 * q + 1];
        float bb0 = bias1[2 * q], bb1 = bias1[2 * q + 1];
        float v0 = fmaxf(elu1(__uint_as_float(ua << 16) + xa * r0 + bb0),
                         elu1(__uint_as_float(ub << 16) + xb * r0 + bb0));
        float v1 = fmaxf(elu1(__uint_as_float(ua & 0xffff0000u) + xa * r1v + bb1),
                         elu1(__uint_as_float(ub & 0xffff0000u) + xb * r1v + bb1));
        x1_lds[ln][q] = pk_bf16(v0, v1);
    }
    __syncthreads();

    // hoist root2 column o (reused for all 26 node evaluations per thread)
    float r2[C1];
#pragma unroll
    for (int i = 0; i < C1; ++i) r2[i] = root2[i * C2 + o];
    float bo = bias2[o];

    float sum = 0.f;
    for (int jj = w; jj < 50; jj += 4) {
        int j = b * 50 + jj;
        float hv[2];
#pragma unroll
        for (int tt = 0; tt < 2; ++tt) {
            int ln = 2 * jj + tt;
            int n = b * 100 + ln;
            float a = bf2f(agg2b[(size_t)n * C2 + o]) + bo;
            const int4v* xp = (const int4v*)&x1_lds[ln][0];
#pragma unroll
            for (int q = 0; q < 4; ++q) {
                int4v v4 = xp[q];
#pragma unroll
                for (int g2 = 0; g2 < 4; ++g2) {
                    unsigned int u = (unsigned int)v4[g2];
                    a = fmaf(__uint_as_float(u << 16),         r2[q * 8 + 2 * g2],     a);
                    a = fmaf(__uint_as_float(u & 0xffff0000u), r2[q * 8 + 2 * g2 + 1], a);
                }
            }
            hv[tt] = elu1(a);
        }
        sum += fmaxf(hv[0], hv[1]);
        (void)j;
    }
    part[w][o] = sum;
    __syncthreads();
    if (w == 0)
        gs[o] = (part[0][o] + part[1][o] + part[2][o] + part[3][o]) * (1.f / 50.f);
    __syncthreads();
    if (t < 128) {
        float z = fc1b[t];
#pragma unroll
        for (int i = 0; i < C2; ++i) z = fmaf(gs[i], fc1w[i * 128 + t], z);
        zs[t] = elu1(z);
    }
    __syncthreads();
    if (t < NCLS) {
        float l = fc2b[t];
#pragma unroll
        for (int k = 0; k < 128; ++k) l = fmaf(zs[k], fc2w[k * NCLS + t], l);
        ls[t] = l;
    }
    __syncthreads();
    if (t < NCLS) {
        float mx = ls[0];
#pragma unroll
        for (int cc = 1; cc < NCLS; ++cc) mx = fmaxf(mx, ls[cc]);
        float se = 0.f;
#pragma unroll
        for (int cc = 0; cc < NCLS; ++cc) se += expf(ls[cc] - mx);
        out[b * NCLS + t] = ls[t] - mx - logf(se);
    }
}

extern "C" void kernel_launch(void* const* d_in, const int* in_sizes, int n_in,
                              void* d_out, int out_size, void* d_ws, size_t ws_size,
                              hipStream_t stream)
{
    const float* x    = (const float*)d_in[0];
    const float* pos  = (const float*)d_in[1];
    const int*   ei   = (const int*)d_in[2];
    const float* ea   = (const float*)d_in[3];
    const int*   ei2  = (const int*)d_in[6];
    const float* n1w1 = (const float*)d_in[8];
    const float* n1b1 = (const float*)d_in[9];
    const float* n1w2 = (const float*)d_in[10];
    const float* n1b2 = (const float*)d_in[11];
    const float* root1= (const float*)d_in[12];
    const float* bias1= (const float*)d_in[13];
    const float* n2w1 = (const float*)d_in[14];
    const float* n2b1 = (const float*)d_in[15];
    const float* n2w2 = (const float*)d_in[16];
    const float* n2b2 = (const float*)d_in[17];
    const float* root2= (const float*)d_in[18];
    const float* bias2= (const float*)d_in[19];
    const float* fc1w = (const float*)d_in[20];
    const float* fc1b = (const float*)d_in[21];
    const float* fc2w = (const float*)d_in[22];
    const float* fc2b = (const float*)d_in[23];
    float* out = (float*)d_out;

    // zero region first (single memset): agg1b | agg2b | maxbits
    char* w = (char*)d_ws;
    unsigned short* agg1b = (unsigned short*)w;  w += (size_t)N_NODES * C1 * 2;   // 12.8 MB
    unsigned short* agg2b = (unsigned short*)w;  w += (size_t)N1P * C2 * 2;       // 12.8 MB
    unsigned int* maxbits = (unsigned int*)w;    w += 1024;
    size_t zero_bytes = (size_t)N_NODES * C1 * 2 + (size_t)N1P * C2 * 2 + 1024;
    unsigned int* Bg = (unsigned int*)w;         w += 26624 * 4;

    hipMemsetAsync(agg1b, 0, zero_bytes, stream);

    conv1_kernel<<<CONV1_BLKS + BG_BLKS, 256, 0, stream>>>(
        x, ea, ei, n1w1, n1b1, n1w2, n1b2, n2w2, n2b2, pos, ei2, Bg, maxbits, agg1b);
    conv2_kernel<<<(E2P + 255) / 256, 256, 0, stream>>>(
        ei2, pos, agg1b, x, root1, bias1, n2w1, n2b1, maxbits, Bg, agg2b);
    pool2_head_kernel<<<BGR, 256, 0, stream>>>(
        agg2b, agg1b, x, root1, bias1, root2, bias2,
        fc1w, fc1b, fc2w, fc2b, out);
}